// Round 10
// baseline (20.480 us; speedup 1.0000x reference)
//
#include <hip/hip_runtime.h>

#define NUM_NODES 10000
#define TSTEPS 1440
#define VCOLS 360          // 1440/4 float4 columns
#define PVC 364            // padded f4 row stride: 5824 B = 91 cache lines
#define NPART 250          // partial rows (one per stage-1 block)
#define RPB 40             // rows per block: 250 * 40 = 10000 exactly

__device__ __forceinline__ void f4add(float4& a, const float4 b) {
    a.x += b.x; a.y += b.y; a.z += b.z; a.w += b.w;
}

// DIAGNOSTIC ROUND (structure identical to round 9, stage 2 launched TWICE).
// r9 = 17.5us but floor arithmetic says ~11-12: ~6us is unattributed and both
// kernels are below profiler top-5 visibility. Double-launching stage 2 is
// the clean split: both S2 invocations read L2/L3-warm partials (same as the
// single launch in r9), write identical values to d_out (deterministic).
//   total_r10 - total_r9 = S2 + ~0.25us overhead  =>  S1 = 17.5 - delta.
// (A stage-1 duplicate would NOT be clean: its second run reads L3-warm
// noise and would understate S1.)

// Stage 1: block b sums rows [40b, 40b+40) -> part[b][0..359].
__global__ __launch_bounds__(384, 4) void partial_sum_kernel(
        const float* __restrict__ noise, float4* __restrict__ part) {
    int vc = threadIdx.x;            // 0..383
    int b  = blockIdx.x;             // 0..249
    if (vc < VCOLS) {
        const float4* p = (const float4*)noise + (size_t)b * RPB * VCOLS + vc;
        float4 acc = make_float4(0.f, 0.f, 0.f, 0.f);
        #pragma unroll 1             // keep 8 loads in flight, ~40 VGPR
        for (int it = 0; it < RPB / 8; ++it) {
            float4 v0 = p[0 * VCOLS], v1 = p[1 * VCOLS];
            float4 v2 = p[2 * VCOLS], v3 = p[3 * VCOLS];
            float4 v4 = p[4 * VCOLS], v5 = p[5 * VCOLS];
            float4 v6 = p[6 * VCOLS], v7 = p[7 * VCOLS];
            p += 8 * VCOLS;
            f4add(v0, v1); f4add(v2, v3); f4add(v4, v5); f4add(v6, v7);
            f4add(v0, v2); f4add(v4, v6);
            f4add(v0, v4);
            f4add(acc, v0);
        }
        part[(size_t)b * PVC + vc] = acc;
    }
}

// Stage 2: 90 blocks x 256 threads; thread (c4 = tid&3, jr = tid>>2) reads
// rows j = jr, jr+64, jr+128 (+ jr+192 if jr<58) of its f4-column; LDS tree
// + wave-0 shuffle + fused finalize.
// overall[t] = 0.8*colmean + 0.5 + 0.3*sin(2pi*(10/3600)*time[t])
//   (mean over nodes of sin(theta_t + i*2pi/N) is exactly 0: equally spaced
//    phases over a full circle -> sum of N-th roots of unity = 0)
// encrypted[t] = sin(0.5*overall[t]); out = [encrypted(1440) | overall(1440)]
__global__ __launch_bounds__(256, 4) void reduce_finalize_kernel(
        const float* __restrict__ time_tensor,
        const float4* __restrict__ part,
        float* __restrict__ out) {
    int tid = threadIdx.x;
    int c4  = tid & 3;               // f4-col within tile (0..3)
    int jr  = tid >> 2;              // 0..63
    int c4g = blockIdx.x * 4 + c4;   // global f4-col 0..359

    const float4* q = part + c4g;
    float4 a0 = q[(size_t)jr * PVC];
    float4 b0 = q[(size_t)(jr + 64) * PVC];
    float4 c0 = q[(size_t)(jr + 128) * PVC];
    f4add(a0, c0);
    if (jr < NPART - 192)            // j = jr+192 <= 249
        f4add(b0, q[(size_t)(jr + 192) * PVC]);
    f4add(a0, b0);

    __shared__ float4 red[64][4];
    red[jr][c4] = a0;
    __syncthreads();

    if (tid < 64) {                  // wave 0: jrs = tid>>2 (0..15), cc = tid&3
        int jrs = tid >> 2, cc = tid & 3;
        float4 s = red[jrs][cc];
        f4add(s, red[jrs + 16][cc]);
        f4add(s, red[jrs + 32][cc]);
        f4add(s, red[jrs + 48][cc]);
        #pragma unroll
        for (int off = 32; off >= 4; off >>= 1) {
            s.x += __shfl_down(s.x, off, 64);
            s.y += __shfl_down(s.y, off, 64);
            s.z += __shfl_down(s.z, off, 64);
            s.w += __shfl_down(s.w, off, 64);
        }
        if (tid < 4) {               // lane l holds f4-col blockIdx*4 + l
            int cg = blockIdx.x * 4 + tid;
            const float TWO_PI = 6.2831853071795864769f;
            const float BWF = 10.0f / 3600.0f;
            const float INV_N = 1.0f / NUM_NODES;
            float4 tm = ((const float4*)time_tensor)[cg];
            float4 ov, en;
            ov.x = 0.8f * (s.x * INV_N) + 0.5f + 0.3f * sinf(TWO_PI * BWF * tm.x);
            ov.y = 0.8f * (s.y * INV_N) + 0.5f + 0.3f * sinf(TWO_PI * BWF * tm.y);
            ov.z = 0.8f * (s.z * INV_N) + 0.5f + 0.3f * sinf(TWO_PI * BWF * tm.z);
            ov.w = 0.8f * (s.w * INV_N) + 0.5f + 0.3f * sinf(TWO_PI * BWF * tm.w);
            en.x = sinf(0.5f * ov.x);
            en.y = sinf(0.5f * ov.y);
            en.z = sinf(0.5f * ov.z);
            en.w = sinf(0.5f * ov.w);
            ((float4*)out)[TSTEPS / 4 + cg] = ov;   // overall   [1440, 2880)
            ((float4*)out)[cg] = en;                // encrypted [0, 1440)
        }
    }
}

extern "C" void kernel_launch(void* const* d_in, const int* in_sizes, int n_in,
                              void* d_out, int out_size, void* d_ws, size_t ws_size,
                              hipStream_t stream) {
    const float* time_tensor = (const float*)d_in[0];   // [1440]
    const float* noise       = (const float*)d_in[1];   // [10000, 1440]
    float* out   = (float*)d_out;                       // [2880]
    float4* part = (float4*)d_ws;                       // 250*364 f4 = 1.46 MB

    partial_sum_kernel<<<NPART, 384, 0, stream>>>(noise, part);
    // S2 launched twice: identical inputs -> identical output (deterministic).
    // Delta vs round 9 isolates S2's duration (both runs L2/L3-warm).
    reduce_finalize_kernel<<<VCOLS / 4, 256, 0, stream>>>(time_tensor, part, out);
    reduce_finalize_kernel<<<VCOLS / 4, 256, 0, stream>>>(time_tensor, part, out);
}

// Round 11
// 16.085 us; speedup vs baseline: 1.2732x; 1.2732x over previous
//
#include <hip/hip_runtime.h>

#define NUM_NODES 10000
#define TSTEPS 1440
#define VCOLS 360          // 1440/4 float4 columns
#define PVC 364            // padded f4 row stride: 5824 B = 91 cache lines
#define NPART 250          // partial rows (one per stage-1 block)
#define RPB 40             // rows per block: 250 * 40 = 10000 exactly

typedef float f4v __attribute__((ext_vector_type(4)));  // nontemporal-load-able

__device__ __forceinline__ void f4add(float4& a, const float4 b) {
    a.x += b.x; a.y += b.y; a.z += b.z; a.w += b.w;
}

// ROUND 11: single variable vs round 9 — stage-1 loads are NON-TEMPORAL.
// Measured split (r9/r10 double-launch): S1 ~= 14.3 us (4.0 TB/s read),
// S2 ~= 2.7 us, overhead ~= 0.5 us. S1 is occupancy-insensitive (r5: 24
// waves/CU, r9: 6 waves/CU, same time) -> not latency-bound. Hypothesis:
// the read path pays L1/L3 fill-allocate (r8 profile: FETCH 34 MB < 57.6 MB
// proves reads allocate into L3); 'nt' marks the stream no-reuse.

// Stage 1: block b sums rows [40b, 40b+40) -> part[b][0..359].
__global__ __launch_bounds__(384, 4) void partial_sum_kernel(
        const float* __restrict__ noise, float4* __restrict__ part) {
    int vc = threadIdx.x;            // 0..383
    int b  = blockIdx.x;             // 0..249
    if (vc < VCOLS) {
        const f4v* p = (const f4v*)noise + (size_t)b * RPB * VCOLS + vc;
        f4v acc = (f4v)(0.0f);
        #pragma unroll 1             // keep 8 loads in flight, ~40 VGPR
        for (int it = 0; it < RPB / 8; ++it) {
            f4v v0 = __builtin_nontemporal_load(p + 0 * VCOLS);
            f4v v1 = __builtin_nontemporal_load(p + 1 * VCOLS);
            f4v v2 = __builtin_nontemporal_load(p + 2 * VCOLS);
            f4v v3 = __builtin_nontemporal_load(p + 3 * VCOLS);
            f4v v4 = __builtin_nontemporal_load(p + 4 * VCOLS);
            f4v v5 = __builtin_nontemporal_load(p + 5 * VCOLS);
            f4v v6 = __builtin_nontemporal_load(p + 6 * VCOLS);
            f4v v7 = __builtin_nontemporal_load(p + 7 * VCOLS);
            p += 8 * VCOLS;
            v0 += v1; v2 += v3; v4 += v5; v6 += v7;
            v0 += v2; v4 += v6;
            v0 += v4;
            acc += v0;
        }
        ((f4v*)part)[(size_t)b * PVC + vc] = acc;   // plain store (reused by S2)
    }
}

// Stage 2: byte-identical to round 9. 90 blocks x 256 threads; thread
// (c4 = tid&3, jr = tid>>2) reads rows j = jr, jr+64, jr+128 (+ jr+192 if
// jr<58) of its f4-column; LDS tree + wave-0 shuffle + fused finalize.
// overall[t] = 0.8*colmean + 0.5 + 0.3*sin(2pi*(10/3600)*time[t])
//   (mean over nodes of sin(theta_t + i*2pi/N) is exactly 0: equally spaced
//    phases over a full circle -> sum of N-th roots of unity = 0)
// encrypted[t] = sin(0.5*overall[t]); out = [encrypted(1440) | overall(1440)]
__global__ __launch_bounds__(256, 4) void reduce_finalize_kernel(
        const float* __restrict__ time_tensor,
        const float4* __restrict__ part,
        float* __restrict__ out) {
    int tid = threadIdx.x;
    int c4  = tid & 3;               // f4-col within tile (0..3)
    int jr  = tid >> 2;              // 0..63
    int c4g = blockIdx.x * 4 + c4;   // global f4-col 0..359

    const float4* q = part + c4g;
    float4 a0 = q[(size_t)jr * PVC];
    float4 b0 = q[(size_t)(jr + 64) * PVC];
    float4 c0 = q[(size_t)(jr + 128) * PVC];
    f4add(a0, c0);
    if (jr < NPART - 192)            // j = jr+192 <= 249
        f4add(b0, q[(size_t)(jr + 192) * PVC]);
    f4add(a0, b0);

    __shared__ float4 red[64][4];
    red[jr][c4] = a0;
    __syncthreads();

    if (tid < 64) {                  // wave 0: jrs = tid>>2 (0..15), cc = tid&3
        int jrs = tid >> 2, cc = tid & 3;
        float4 s = red[jrs][cc];
        f4add(s, red[jrs + 16][cc]);
        f4add(s, red[jrs + 32][cc]);
        f4add(s, red[jrs + 48][cc]);
        #pragma unroll
        for (int off = 32; off >= 4; off >>= 1) {
            s.x += __shfl_down(s.x, off, 64);
            s.y += __shfl_down(s.y, off, 64);
            s.z += __shfl_down(s.z, off, 64);
            s.w += __shfl_down(s.w, off, 64);
        }
        if (tid < 4) {               // lane l holds f4-col blockIdx*4 + l
            int cg = blockIdx.x * 4 + tid;
            const float TWO_PI = 6.2831853071795864769f;
            const float BWF = 10.0f / 3600.0f;
            const float INV_N = 1.0f / NUM_NODES;
            float4 tm = ((const float4*)time_tensor)[cg];
            float4 ov, en;
            ov.x = 0.8f * (s.x * INV_N) + 0.5f + 0.3f * sinf(TWO_PI * BWF * tm.x);
            ov.y = 0.8f * (s.y * INV_N) + 0.5f + 0.3f * sinf(TWO_PI * BWF * tm.y);
            ov.z = 0.8f * (s.z * INV_N) + 0.5f + 0.3f * sinf(TWO_PI * BWF * tm.z);
            ov.w = 0.8f * (s.w * INV_N) + 0.5f + 0.3f * sinf(TWO_PI * BWF * tm.w);
            en.x = sinf(0.5f * ov.x);
            en.y = sinf(0.5f * ov.y);
            en.z = sinf(0.5f * ov.z);
            en.w = sinf(0.5f * ov.w);
            ((float4*)out)[TSTEPS / 4 + cg] = ov;   // overall   [1440, 2880)
            ((float4*)out)[cg] = en;                // encrypted [0, 1440)
        }
    }
}

extern "C" void kernel_launch(void* const* d_in, const int* in_sizes, int n_in,
                              void* d_out, int out_size, void* d_ws, size_t ws_size,
                              hipStream_t stream) {
    const float* time_tensor = (const float*)d_in[0];   // [1440]
    const float* noise       = (const float*)d_in[1];   // [10000, 1440]
    float* out   = (float*)d_out;                       // [2880]
    float4* part = (float4*)d_ws;                       // 250*364 f4 = 1.46 MB

    partial_sum_kernel<<<NPART, 384, 0, stream>>>(noise, part);
    reduce_finalize_kernel<<<VCOLS / 4, 256, 0, stream>>>(time_tensor, part, out);
}